// Round 6
// baseline (43.273 us; speedup 1.0000x reference)
//
#include <hip/hip_runtime.h>
#include <cstdint>
#include <cstddef>

// ---------------------------------------------------------------------------
// Problem constants
// ---------------------------------------------------------------------------
#define BB 2
#define PP 4
#define CC 3
#define HWSZ 65536            // H*W
#define BGH 2764
#define BGW 3856
#define NTAO 27               // 3 lifes x 9 linspace points
#define X4_SIZE (BB*PP*HWSZ)              // 524288
#define TAO_OFF X4_SIZE
#define TAO_SIZE (BB*NTAO*HWSZ)           // 3538944
#define OUT2_OFF (TAO_OFF + TAO_SIZE)     // 4063232
#define NPK 24                            // poisson draws shipped (P(>24)~1e-16)
#define NBLK_A 2048                       // kA blocks

// ---------------------------------------------------------------------------
// rotl via v_alignbit_b32
// ---------------------------------------------------------------------------
__host__ __device__ inline uint32_t rotl32(uint32_t x, int r) {
#ifdef __HIP_DEVICE_COMPILE__
  return __builtin_amdgcn_alignbit(x, x, 32 - r);
#else
  return (x << r) | (x >> (32 - r));
#endif
}

// ---------------------------------------------------------------------------
// Threefry-2x32-20 (jax partitionable mode — verified r2..r5)
// ---------------------------------------------------------------------------
__host__ __device__ inline void tf2x32(uint32_t k0, uint32_t k1,
                                       uint32_t x0, uint32_t x1,
                                       uint32_t& o0, uint32_t& o1) {
  uint32_t ks2 = k0 ^ k1 ^ 0x1BD11BDAu;
  x0 += k0; x1 += k1;
#define TF_RND(r) { x0 += x1; x1 = rotl32(x1, r); x1 ^= x0; }
  TF_RND(13) TF_RND(15) TF_RND(26) TF_RND(6)
  x0 += k1;  x1 += ks2 + 1u;
  TF_RND(17) TF_RND(29) TF_RND(16) TF_RND(24)
  x0 += ks2; x1 += k0 + 2u;
  TF_RND(13) TF_RND(15) TF_RND(26) TF_RND(6)
  x0 += k0;  x1 += k1 + 3u;
  TF_RND(17) TF_RND(29) TF_RND(16) TF_RND(24)
  x0 += k1;  x1 += ks2 + 4u;
  TF_RND(13) TF_RND(15) TF_RND(26) TF_RND(6)
  x0 += ks2; x1 += k0 + 5u;
#undef TF_RND
  o0 = x0; o1 = x1;
}

__host__ __device__ inline uint32_t bits32(uint32_t k0, uint32_t k1, uint32_t e) {
  uint32_t o0, o1;
  tf2x32(k0, k1, 0u, e, o0, o1);
  return o0 ^ o1;
}

// partitionable split: subkey i = RAW pair threefry(key, (0,i))
static void jax_split(uint32_t k0, uint32_t k1, int n, uint32_t (*keys)[2]) {
  for (int i = 0; i < n; ++i)
    tf2x32(k0, k1, 0u, (uint32_t)i, keys[i][0], keys[i][1]);
}

__host__ __device__ inline float u01(uint32_t bits) {
  uint32_t fb = (bits >> 9) | 0x3F800000u;
  return __builtin_bit_cast(float, fb) - 1.0f;
}

// ---------------------------------------------------------------------------
// erfinv (Giles poly == XLA ErfInv32)
// ---------------------------------------------------------------------------
__device__ inline float erfinv_f(float x) {
  float w = -log1pf(-x * x);
  float p;
  if (w < 5.0f) {
    w = w - 2.5f;
    p = 2.81022636e-08f;
    p = fmaf(p, w, 3.43273939e-07f);
    p = fmaf(p, w, -3.5233877e-06f);
    p = fmaf(p, w, -4.39150654e-06f);
    p = fmaf(p, w, 0.00021858087f);
    p = fmaf(p, w, -0.00125372503f);
    p = fmaf(p, w, -0.00417768164f);
    p = fmaf(p, w, 0.246640727f);
    p = fmaf(p, w, 1.50140941f);
  } else {
    w = sqrtf(w) - 3.0f;
    p = -0.000200214257f;
    p = fmaf(p, w, 0.000100950558f);
    p = fmaf(p, w, 0.00134934322f);
    p = fmaf(p, w, -0.00367342844f);
    p = fmaf(p, w, 0.00573950773f);
    p = fmaf(p, w, -0.0076224613f);
    p = fmaf(p, w, 0.00943887047f);
    p = fmaf(p, w, 1.00167406f);
    p = fmaf(p, w, 2.83297682f);
  }
  return p * x;
}

__device__ inline float normal_e(uint32_t k0, uint32_t k1, uint32_t e) {
  float f = u01(bits32(k0, k1, e));
  const float LO = -0.99999994f;
  float u = fmaxf(LO, fmaf(f, 2.0f, LO));
  return 1.41421356237f * erfinv_f(u);
}

struct PCParams {
  uint32_t kn0, kn1;        // k_norm
  uint32_t kb0, kb1;        // k_bgn
  uint32_t s1[NPK * 2];     // poisson chain subkeys for k_p1
  uint32_t s2[NPK * 2];     // poisson chain subkeys for k_p2
  float bg1[8], bg2[8];
  int idx;
};

// ---------------------------------------------------------------------------
// Gaussian ladder: q_j = exp(-(d0+10j)^2*inv) = q0 * A^j * B^(j^2);
// 3 exps + muls instead of 9. Accumulates tg9, returns decay.
// ---------------------------------------------------------------------------
__device__ inline float decay_pc(uint32_t kl0, uint32_t kl1, uint32_t ks0,
                                 uint32_t ks1, uint32_t e,
                                 const float (*et)[4], int p, float* tg9) {
  float ul = u01(bits32(kl0, kl1, e));
  float us = u01(bits32(ks0, ks1, e));
  float d0 = -40.0f - (ul - 0.5f) * 12.0f;   // tao0 - Lr (life cancels)
  float sr = fmaf(us - 0.5f, 0.6f, 6.0f);
  float inv = __builtin_amdgcn_rcpf(2.0f * sr * sr);
  float q[9];
  float A  = __expf(-20.0f * inv * d0);
  float Bm = __expf(-100.0f * inv);
  float B2 = Bm * Bm;
  q[0] = __expf(-(d0 * d0) * inv);
  float m = A * Bm;
  float s = q[0];
#pragma unroll
  for (int j = 1; j < 9; ++j) {
    q[j] = q[j - 1] * m;
    m *= B2;
    s += q[j];
  }
  float rs = __builtin_amdgcn_rcpf(s);
  float dec = 0.0f;
#pragma unroll
  for (int j = 0; j < 9; ++j) {
    float wn = q[j] * rs;
    tg9[j] += wn;
    dec = fmaf(et[j][p], wn, dec);
  }
  return dec;
}

// ---------------------------------------------------------------------------
// Kernel A: 2048 blocks x 256. Thread = (b, p=wave, hw = hwg*64+lane).
// x2 per-thread sum over c; tao_gt p-mean via single-barrier LDS exchange;
// block max -> bmax[blockIdx] (no atomics).
// ---------------------------------------------------------------------------
__global__ __launch_bounds__(256) void kA(
    const float* __restrict__ x, const float* __restrict__ t,
    const float* __restrict__ ratio, const float* __restrict__ life,
    const float* __restrict__ inten, float* __restrict__ out,
    float* __restrict__ bmax,
    uint32_t kl0, uint32_t kl1, uint32_t ks0, uint32_t ks1) {
  __shared__ float et_s[NTAO][4];
  __shared__ float inten_s[3];
  __shared__ float tg_lds[4][NTAO][64];   // 27648 B
  __shared__ float bmax_s[4];
  const int tid = threadIdx.x;
  if (tid < NTAO * 4) {
    int j = tid >> 2, p = tid & 3;
    float tao = life[j / 9] + (-40.0f + 10.0f * (float)(j % 9));
    float Tp = fmaxf(t[p] * ratio[p] * 1000.0f, 0.0f);
    et_s[j][p] = expf((-Tp) / tao);   // prologue only: libm accuracy
  }
  if (tid < 3) inten_s[tid] = inten[tid];
  __syncthreads();

  const int blk = blockIdx.x;
  const int b = blk >> 10;
  const int hwg = blk & 1023;
  const int p = tid >> 6;               // wave id = p
  const int lane = tid & 63;
  const int hw = hwg * 64 + lane;

  float acc = 0.0f;

#pragma unroll
  for (int c = 0; c < 3; ++c) {
    float tg9[9];
#pragma unroll
    for (int j = 0; j < 9; ++j) tg9[j] = 0.0f;

    const uint32_t e = (uint32_t)((((b * 4 + p) * 3 + c) << 16) + hw);
    float dec = decay_pc(kl0, kl1, ks0, ks1, e,
                         (const float(*)[4])&et_s[c * 9], p, tg9);
    acc = fmaf(x[e] * dec, inten_s[c], acc);

#pragma unroll
    for (int j = 0; j < 9; ++j) tg_lds[p][c * 9 + j][lane] = tg9[j];
  }
  __syncthreads();

  // p-mean read phase: 27*64 = 1728 items block-strided over 256 threads
#pragma unroll
  for (int it = tid; it < NTAO * 64; it += 256) {
    int row = it >> 6, ln = it & 63;
    float s = ((tg_lds[0][row][ln] + tg_lds[1][row][ln]) +
               (tg_lds[2][row][ln] + tg_lds[3][row][ln]));
    out[TAO_OFF + ((b * NTAO + row) << 16) + hwg * 64 + ln] = s * 0.25f;
  }

  out[((b * 4 + p) << 16) + hw] = acc;   // x2 staged in the x4 slot

  // block max (x2 >= 0), no atomics
  float m = acc;
#pragma unroll
  for (int off = 32; off; off >>= 1) m = fmaxf(m, __shfl_xor(m, off));
  if (lane == 0) bmax_s[p] = m;
  __syncthreads();
  if (tid == 0)
    bmax[blk] = fmaxf(fmaxf(bmax_s[0], bmax_s[1]),
                      fmaxf(bmax_s[2], bmax_s[3]));
}

// ---------------------------------------------------------------------------
// Kernel C: lane-pair split — 2 threads per element.
// parity 0: Poisson(2) chain + k_norm normal + final store
// parity 1: Poisson(xm) chain + bg normal + patch
// Block prologue reduces the 2048 bmax values (replaces kMax dispatch).
// ---------------------------------------------------------------------------
__global__ __launch_bounds__(256) void kC(
    const float* __restrict__ bgf, const float* __restrict__ t,
    const float* __restrict__ ratio, float* __restrict__ out,
    const float* __restrict__ bmax, PCParams pc) {
  __shared__ float red_s[4];
  __shared__ float mx_s;
  const int tid = threadIdx.x;

  // --- global max from bmax[2048]
  float m = 0.0f;
#pragma unroll
  for (int k = 0; k < 8; ++k) m = fmaxf(m, bmax[tid + 256 * k]);
#pragma unroll
  for (int off = 32; off; off >>= 1) m = fmaxf(m, __shfl_xor(m, off));
  if ((tid & 63) == 0) red_s[tid >> 6] = m;
  __syncthreads();
  if (tid == 0)
    mx_s = fmaxf(fmaxf(red_s[0], red_s[1]), fmaxf(red_s[2], red_s[3]));
  __syncthreads();
  const float mx = mx_s;

  if (blockIdx.x == 0 && tid < 8)
    out[OUT2_OFF + tid] = (tid < 4) ? t[tid] * ratio[tid] : ratio[tid - 4];

  const int t2 = blockIdx.x * 256 + tid;   // [0, 1048576)
  const int e = t2 >> 1;
  const int parity = t2 & 1;                // 0: chain2+n ; 1: chain1+patch

  const int bp = e >> 16;
  const int rcc = e & 0xFFFF;
  const int r = rcc >> 8;
  const int cc = rcc & 255;

  const float x2 = out[e];
  const float xm = x2 * __builtin_amdgcn_rcpf(mx + 0.0001f);

  // one normal per lane (k_norm stream on even, k_bgn stream on odd)
  const int row = pc.idx + r;
  const int pp = bp & 3;
  const uint32_t ebg = (uint32_t)((bp * BGH + row) * BGW + cc);
  uint32_t nk0 = parity ? pc.kb0 : pc.kn0;
  uint32_t nk1 = parity ? pc.kb1 : pc.kn1;
  uint32_t ne  = parity ? ebg : (uint32_t)e;
  float nval = normal_e(nk0, nk1, ne);

  float patch = 0.0f;
  if (parity) {
    float bg = bgf[(pp * BGH + row) * BGW + cc];
    patch = (bg * pc.bg1[bp] + nval * pc.bg2[bp]) * 0.1f;
  }

  // one Knuth Poisson chain per lane
  float lam = parity ? fmaxf(xm, 0.0f) : 2.0f;
  const bool zz = !(lam > 0.0f);
  const float neg = -lam;
  float lp = 0.0f;
  int k = 0;
#pragma clang loop unroll(disable)
  for (int i = 0; i < NPK; ++i) {
    bool c = (!zz) && (lp > neg);
    if (!__any(c)) break;
    if (c) {
      k++;
      uint32_t key0 = parity ? pc.s1[2 * i]     : pc.s2[2 * i];
      uint32_t key1 = parity ? pc.s1[2 * i + 1] : pc.s2[2 * i + 1];
      lp += __logf(u01(bits32(key0, key1, (uint32_t)e)));
    }
  }
  float pk = zz ? 0.0f : (float)(k - 1);    // even: po ; odd: pi

  // exchange within the lane pair
  float pi_o    = __shfl_xor(pk, 1);        // even receives odd's pi
  float patch_o = __shfl_xor(patch, 1);     // even receives odd's patch

  if (!parity) {
    float n_int = fmaf(xm, 5.0f, nval);
    float v = (((n_int + pi_o) + pk) + x2) + patch_o;
    v = fminf(fmaxf(v, 0.0f), 255.0f);
    out[e] = v * (1.0f / 255.0f);
  }
}

// ---------------------------------------------------------------------------
// Host
// ---------------------------------------------------------------------------
extern "C" void kernel_launch(void* const* d_in, const int* in_sizes, int n_in,
                              void* d_out, int out_size, void* d_ws, size_t ws_size,
                              hipStream_t stream) {
  const float* x     = (const float*)d_in[0];
  const float* t     = (const float*)d_in[1];
  const float* ratio = (const float*)d_in[2];
  const float* life  = (const float*)d_in[3];
  const float* inten = (const float*)d_in[4];
  const float* bgf   = (const float*)d_in[5];
  float* out = (float*)d_out;
  float* bmax = (float*)d_ws;            // [0, 2048): per-block maxes

  // key(42) = (0,42) -> 9 subkeys:
  // k_life, k_sig, k_norm, k_p1, k_p2, k_bg1, k_bg2, k_bgn, k_idx
  uint32_t sk[9][2];
  jax_split(0u, 42u, 9, sk);

  PCParams pc;
  pc.kn0 = sk[2][0]; pc.kn1 = sk[2][1];
  pc.kb0 = sk[7][0]; pc.kb1 = sk[7][1];

  // poisson knuth chains: rng, subkey = split(rng) per iteration
  {
    uint32_t r0 = sk[3][0], r1 = sk[3][1];
    for (int i = 0; i < NPK; ++i) {
      uint32_t two[2][2];
      jax_split(r0, r1, 2, two);
      pc.s1[2*i] = two[1][0]; pc.s1[2*i+1] = two[1][1];
      r0 = two[0][0]; r1 = two[0][1];
    }
    r0 = sk[4][0]; r1 = sk[4][1];
    for (int i = 0; i < NPK; ++i) {
      uint32_t two[2][2];
      jax_split(r0, r1, 2, two);
      pc.s2[2*i] = two[1][0]; pc.s2[2*i+1] = two[1][1];
      r0 = two[0][0]; r1 = two[0][1];
    }
  }

  for (uint32_t i = 0; i < 8; ++i) {
    pc.bg1[i] = u01(bits32(sk[5][0], sk[5][1], i)) * 0.5f + 0.5f;
    pc.bg2[i] = u01(bits32(sk[6][0], sk[6][1], i)) * 0.5f + 0.5f;
  }

  // idx = randint(k_idx, (), 0, 9): exact jax double-word algorithm
  {
    uint32_t hi = bits32(sk[8][0], sk[8][1], 0u);
    uint32_t lo = bits32(sk[8][0], sk[8][1], 1u);
    const uint32_t span = 9u;
    uint32_t mult = (65536u % span);
    mult = (mult * mult) % span;
    uint32_t off = ((hi % span) * mult + (lo % span)) % span;
    pc.idx = (int)off;
  }

  kA<<<NBLK_A, 256, 0, stream>>>(x, t, ratio, life, inten, out, bmax,
                                 sk[0][0], sk[0][1], sk[1][0], sk[1][1]);
  kC<<<(2 * X4_SIZE) / 256, 256, 0, stream>>>(bgf, t, ratio, out, bmax, pc);
}

// Round 8
// 39.531 us; speedup vs baseline: 1.0947x; 1.0947x over previous
//
#include <hip/hip_runtime.h>
#include <cstdint>
#include <cstddef>

// ---------------------------------------------------------------------------
// Problem constants
// ---------------------------------------------------------------------------
#define BB 2
#define PP 4
#define CC 3
#define HWSZ 65536            // H*W
#define BGH 2764
#define BGW 3856
#define NTAO 27               // 3 lifes x 9 linspace points
#define X4_SIZE (BB*PP*HWSZ)              // 524288
#define TAO_OFF X4_SIZE
#define TAO_SIZE (BB*NTAO*HWSZ)           // 3538944
#define OUT2_OFF (TAO_OFF + TAO_SIZE)     // 4063232
#define NPK 24                            // poisson draws shipped (P(>24)~1e-16)
#define NPB 4                             // draws per batch (ILP)
#define NBLK_A 2048                       // kA blocks

// ---------------------------------------------------------------------------
// rotl via v_alignbit_b32
// ---------------------------------------------------------------------------
__host__ __device__ inline uint32_t rotl32(uint32_t x, int r) {
#ifdef __HIP_DEVICE_COMPILE__
  return __builtin_amdgcn_alignbit(x, x, 32 - r);
#else
  return (x << r) | (x >> (32 - r));
#endif
}

// ---------------------------------------------------------------------------
// Threefry-2x32-20 (jax partitionable mode — verified r2..r6)
// ---------------------------------------------------------------------------
__host__ __device__ inline void tf2x32(uint32_t k0, uint32_t k1,
                                       uint32_t x0, uint32_t x1,
                                       uint32_t& o0, uint32_t& o1) {
  uint32_t ks2 = k0 ^ k1 ^ 0x1BD11BDAu;
  x0 += k0; x1 += k1;
#define TF_RND(r) { x0 += x1; x1 = rotl32(x1, r); x1 ^= x0; }
  TF_RND(13) TF_RND(15) TF_RND(26) TF_RND(6)
  x0 += k1;  x1 += ks2 + 1u;
  TF_RND(17) TF_RND(29) TF_RND(16) TF_RND(24)
  x0 += ks2; x1 += k0 + 2u;
  TF_RND(13) TF_RND(15) TF_RND(26) TF_RND(6)
  x0 += k0;  x1 += k1 + 3u;
  TF_RND(17) TF_RND(29) TF_RND(16) TF_RND(24)
  x0 += k1;  x1 += ks2 + 4u;
  TF_RND(13) TF_RND(15) TF_RND(26) TF_RND(6)
  x0 += ks2; x1 += k0 + 5u;
#undef TF_RND
  o0 = x0; o1 = x1;
}

__host__ __device__ inline uint32_t bits32(uint32_t k0, uint32_t k1, uint32_t e) {
  uint32_t o0, o1;
  tf2x32(k0, k1, 0u, e, o0, o1);
  return o0 ^ o1;
}

// partitionable split: subkey i = RAW pair threefry(key, (0,i))
static void jax_split(uint32_t k0, uint32_t k1, int n, uint32_t (*keys)[2]) {
  for (int i = 0; i < n; ++i)
    tf2x32(k0, k1, 0u, (uint32_t)i, keys[i][0], keys[i][1]);
}

__host__ __device__ inline float u01(uint32_t bits) {
  uint32_t fb = (bits >> 9) | 0x3F800000u;
  return __builtin_bit_cast(float, fb) - 1.0f;
}

// ---------------------------------------------------------------------------
// erfinv (Giles poly == XLA ErfInv32), fast transcendentals:
// w = -log1p(-x^2) -> -__logf(fma(-x,x,1)): rel err ~1e-5, irrelevant vs 2e-2
// ---------------------------------------------------------------------------
__device__ inline float erfinv_f(float x) {
  float w = -__logf(fmaf(-x, x, 1.0f));
  float p;
  if (w < 5.0f) {
    w = w - 2.5f;
    p = 2.81022636e-08f;
    p = fmaf(p, w, 3.43273939e-07f);
    p = fmaf(p, w, -3.5233877e-06f);
    p = fmaf(p, w, -4.39150654e-06f);
    p = fmaf(p, w, 0.00021858087f);
    p = fmaf(p, w, -0.00125372503f);
    p = fmaf(p, w, -0.00417768164f);
    p = fmaf(p, w, 0.246640727f);
    p = fmaf(p, w, 1.50140941f);
  } else {
    w = __builtin_amdgcn_sqrtf(w) - 3.0f;
    p = -0.000200214257f;
    p = fmaf(p, w, 0.000100950558f);
    p = fmaf(p, w, 0.00134934322f);
    p = fmaf(p, w, -0.00367342844f);
    p = fmaf(p, w, 0.00573950773f);
    p = fmaf(p, w, -0.0076224613f);
    p = fmaf(p, w, 0.00943887047f);
    p = fmaf(p, w, 1.00167406f);
    p = fmaf(p, w, 2.83297682f);
  }
  return p * x;
}

__device__ inline float normal_e(uint32_t k0, uint32_t k1, uint32_t e) {
  float f = u01(bits32(k0, k1, e));
  const float LO = -0.99999994f;
  float u = fmaxf(LO, fmaf(f, 2.0f, LO));
  return 1.41421356237f * erfinv_f(u);
}

struct PCParams {
  uint32_t kn0, kn1;        // k_norm
  uint32_t kb0, kb1;        // k_bgn
  uint32_t s1[NPK * 2];     // poisson chain subkeys for k_p1
  uint32_t s2[NPK * 2];     // poisson chain subkeys for k_p2
  float bg1[8], bg2[8];
  int idx;
};

// ---------------------------------------------------------------------------
// Batched Knuth step: 4 independent draws (4-way threefry ILP), prefix sums
// in the reference's exact sequential fp order. Counts are bit-exact because
// log u <= 0 makes the prefix monotone (once stopped, never resumes), and the
// reference's log_prod also accumulates past the stop identically.
// ---------------------------------------------------------------------------
__device__ inline void pk_batch(const uint32_t* __restrict__ sk, int b,
                                uint32_t e, float neg, float& lp, int& k) {
  float l0 = __logf(u01(bits32(sk[(b*NPB+0)*2], sk[(b*NPB+0)*2+1], e)));
  float l1 = __logf(u01(bits32(sk[(b*NPB+1)*2], sk[(b*NPB+1)*2+1], e)));
  float l2 = __logf(u01(bits32(sk[(b*NPB+2)*2], sk[(b*NPB+2)*2+1], e)));
  float l3 = __logf(u01(bits32(sk[(b*NPB+3)*2], sk[(b*NPB+3)*2+1], e)));
  int cnt = (lp > neg) ? 1 : 0;
  float p0 = lp + l0;
  cnt += (p0 > neg) ? 1 : 0;
  float p1 = p0 + l1;
  cnt += (p1 > neg) ? 1 : 0;
  float p2 = p1 + l2;
  cnt += (p2 > neg) ? 1 : 0;
  lp = p2 + l3;
  k += cnt;
}

// ---------------------------------------------------------------------------
// Gaussian ladder: q_j = exp(-(d0+10j)^2*inv) = q0 * A^j * B^(j^2);
// 3 exps + muls instead of 9. Accumulates tg9, returns decay.
// ---------------------------------------------------------------------------
__device__ inline float decay_pc(uint32_t kl0, uint32_t kl1, uint32_t ks0,
                                 uint32_t ks1, uint32_t e,
                                 const float (*et)[4], int p, float* tg9) {
  float ul = u01(bits32(kl0, kl1, e));
  float us = u01(bits32(ks0, ks1, e));
  float d0 = -40.0f - (ul - 0.5f) * 12.0f;   // tao0 - Lr (life cancels)
  float sr = fmaf(us - 0.5f, 0.6f, 6.0f);
  float inv = __builtin_amdgcn_rcpf(2.0f * sr * sr);
  float q[9];
  float A  = __expf(-20.0f * inv * d0);
  float Bm = __expf(-100.0f * inv);
  float B2 = Bm * Bm;
  q[0] = __expf(-(d0 * d0) * inv);
  float m = A * Bm;
  float s = q[0];
#pragma unroll
  for (int j = 1; j < 9; ++j) {
    q[j] = q[j - 1] * m;
    m *= B2;
    s += q[j];
  }
  float rs = __builtin_amdgcn_rcpf(s);
  float dec = 0.0f;
#pragma unroll
  for (int j = 0; j < 9; ++j) {
    float wn = q[j] * rs;
    tg9[j] += wn;
    dec = fmaf(et[j][p], wn, dec);
  }
  return dec;
}

// ---------------------------------------------------------------------------
// Kernel A (r5-proven form): 2048 blocks x 256. Thread = (b, p=wave, hw).
// x2 per-thread sum over c; tao_gt p-mean via LDS; block max -> bmax[blk].
// ---------------------------------------------------------------------------
__global__ __launch_bounds__(256) void kA(
    const float* __restrict__ x, const float* __restrict__ t,
    const float* __restrict__ ratio, const float* __restrict__ life,
    const float* __restrict__ inten, float* __restrict__ out,
    float* __restrict__ bmax,
    uint32_t kl0, uint32_t kl1, uint32_t ks0, uint32_t ks1) {
  __shared__ float et_s[NTAO][4];
  __shared__ float inten_s[3];
  __shared__ float tg_lds[4][9][64];
  __shared__ float bmax_s[4];
  const int tid = threadIdx.x;
  if (tid < NTAO * 4) {
    int j = tid >> 2, p = tid & 3;
    float tao = life[j / 9] + (-40.0f + 10.0f * (float)(j % 9));
    float Tp = fmaxf(t[p] * ratio[p] * 1000.0f, 0.0f);
    et_s[j][p] = expf((-Tp) / tao);   // prologue only: libm accuracy
  }
  if (tid < 3) inten_s[tid] = inten[tid];
  __syncthreads();

  const int blk = blockIdx.x;
  const int b = blk >> 10;
  const int hwg = blk & 1023;
  const int p = tid >> 6;               // wave id = p
  const int lane = tid & 63;
  const int hw = hwg * 64 + lane;

  float acc = 0.0f;

  for (int c = 0; c < 3; ++c) {
    float tg9[9];
#pragma unroll
    for (int j = 0; j < 9; ++j) tg9[j] = 0.0f;

    const uint32_t e = (uint32_t)((((b * 4 + p) * 3 + c) << 16) + hw);
    float dec = decay_pc(kl0, kl1, ks0, ks1, e,
                         (const float(*)[4])&et_s[c * 9], p, tg9);
    acc = fmaf(x[e] * dec, inten_s[c], acc);

    // p-sum of tg9 via LDS (conflict-free: lane fastest)
#pragma unroll
    for (int j = 0; j < 9; ++j) tg_lds[p][j][lane] = tg9[j];
    __syncthreads();
    for (int jj = p; jj < 9; jj += 4) {
      float s = ((tg_lds[0][jj][lane] + tg_lds[1][jj][lane]) +
                 (tg_lds[2][jj][lane] + tg_lds[3][jj][lane]));
      out[TAO_OFF + ((b * NTAO + c * 9 + jj) << 16) + hw] = s * 0.25f;
    }
    __syncthreads();
  }

  out[((b * 4 + p) << 16) + hw] = acc;   // x2 staged in the x4 slot

  // block max (x2 >= 0), no atomics
  float m = acc;
#pragma unroll
  for (int off = 32; off; off >>= 1) m = fmaxf(m, __shfl_xor(m, off));
  if (lane == 0) bmax_s[p] = m;
  __syncthreads();
  if (tid == 0)
    bmax[blk] = fmaxf(fmaxf(bmax_s[0], bmax_s[1]),
                      fmaxf(bmax_s[2], bmax_s[3]));
}

// ---------------------------------------------------------------------------
// Kernel C: noise + background patch -> x4. One thread per element.
// Prologue reduces bmax[2048] (no extra dispatch). Poisson = 4-way batches.
// ---------------------------------------------------------------------------
__global__ __launch_bounds__(256) void kC(
    const float* __restrict__ bgf, const float* __restrict__ t,
    const float* __restrict__ ratio, float* __restrict__ out,
    const float* __restrict__ bmax, PCParams pc) {
  __shared__ float red_s[4];
  __shared__ float mx_s;
  const int tid = threadIdx.x;

  // --- global max from bmax[2048]
  float m = 0.0f;
#pragma unroll
  for (int k = 0; k < 8; ++k) m = fmaxf(m, bmax[tid + 256 * k]);
#pragma unroll
  for (int off = 32; off; off >>= 1) m = fmaxf(m, __shfl_xor(m, off));
  if ((tid & 63) == 0) red_s[tid >> 6] = m;
  __syncthreads();
  if (tid == 0)
    mx_s = fmaxf(fmaxf(red_s[0], red_s[1]), fmaxf(red_s[2], red_s[3]));
  __syncthreads();
  const float mx = mx_s;

  if (blockIdx.x == 0 && tid < 8)
    out[OUT2_OFF + tid] = (tid < 4) ? t[tid] * ratio[tid] : ratio[tid - 4];

  const int e = blockIdx.x * 256 + tid;   // [0, 524288)
  const int bp = e >> 16;
  const int rcc = e & 0xFFFF;
  const int r = rcc >> 8;
  const int cc = rcc & 255;

  // early loads
  const int row = pc.idx + r;
  const int p = bp & 3;
  const float bg = bgf[(p * BGH + row) * BGW + cc];
  const float x2 = out[e];

  // two independent normals (ILP 2)
  const uint32_t ebg = (uint32_t)((bp * BGH + row) * BGW + cc);
  float nb = normal_e(pc.kb0, pc.kb1, ebg);
  float n  = normal_e(pc.kn0, pc.kn1, (uint32_t)e);
  float patch = (bg * pc.bg1[bp] + nb * pc.bg2[bp]) * 0.1f;

  const float xm = x2 * __builtin_amdgcn_rcpf(mx + 0.0001f);
  float n_int = fmaf(xm, 5.0f, n);

  // fused batched Knuth Poisson: chain1 lam=max(xm,0), chain2 lam=2
  float lam1 = fmaxf(xm, 0.0f);
  const bool z1 = !(lam1 > 0.0f);
  const float neg1 = -lam1;
  float lp1 = 0.0f, lp2 = 0.0f;
  int k1 = 0, k2 = 0;
#pragma clang loop unroll(disable)
  for (int b = 0; b < NPK / NPB; ++b) {
    bool a1 = __any((!z1) && (lp1 > neg1));
    bool a2 = __any(lp2 > -2.0f);
    if (!(a1 || a2)) break;
    if (a1) pk_batch(pc.s1, b, (uint32_t)e, neg1, lp1, k1);
    if (a2) pk_batch(pc.s2, b, (uint32_t)e, -2.0f, lp2, k2);
  }
  float pi = z1 ? 0.0f : (float)(k1 - 1);
  float po = (float)(k2 - 1);

  float x3 = ((n_int + pi) + po) + x2;
  float v = x3 + patch;
  v = fminf(fmaxf(v, 0.0f), 255.0f);
  out[e] = v * (1.0f / 255.0f);
}

// ---------------------------------------------------------------------------
// Host
// ---------------------------------------------------------------------------
extern "C" void kernel_launch(void* const* d_in, const int* in_sizes, int n_in,
                              void* d_out, int out_size, void* d_ws, size_t ws_size,
                              hipStream_t stream) {
  const float* x     = (const float*)d_in[0];
  const float* t     = (const float*)d_in[1];
  const float* ratio = (const float*)d_in[2];
  const float* life  = (const float*)d_in[3];
  const float* inten = (const float*)d_in[4];
  const float* bgf   = (const float*)d_in[5];
  float* out = (float*)d_out;
  float* bmax = (float*)d_ws;            // [0, 2048): per-block maxes

  // key(42) = (0,42) -> 9 subkeys:
  // k_life, k_sig, k_norm, k_p1, k_p2, k_bg1, k_bg2, k_bgn, k_idx
  uint32_t sk[9][2];
  jax_split(0u, 42u, 9, sk);

  PCParams pc;
  pc.kn0 = sk[2][0]; pc.kn1 = sk[2][1];
  pc.kb0 = sk[7][0]; pc.kb1 = sk[7][1];

  // poisson knuth chains: rng, subkey = split(rng) per iteration
  {
    uint32_t r0 = sk[3][0], r1 = sk[3][1];
    for (int i = 0; i < NPK; ++i) {
      uint32_t two[2][2];
      jax_split(r0, r1, 2, two);
      pc.s1[2*i] = two[1][0]; pc.s1[2*i+1] = two[1][1];
      r0 = two[0][0]; r1 = two[0][1];
    }
    r0 = sk[4][0]; r1 = sk[4][1];
    for (int i = 0; i < NPK; ++i) {
      uint32_t two[2][2];
      jax_split(r0, r1, 2, two);
      pc.s2[2*i] = two[1][0]; pc.s2[2*i+1] = two[1][1];
      r0 = two[0][0]; r1 = two[0][1];
    }
  }

  for (uint32_t i = 0; i < 8; ++i) {
    pc.bg1[i] = u01(bits32(sk[5][0], sk[5][1], i)) * 0.5f + 0.5f;
    pc.bg2[i] = u01(bits32(sk[6][0], sk[6][1], i)) * 0.5f + 0.5f;
  }

  // idx = randint(k_idx, (), 0, 9): exact jax double-word algorithm
  {
    uint32_t hi = bits32(sk[8][0], sk[8][1], 0u);
    uint32_t lo = bits32(sk[8][0], sk[8][1], 1u);
    const uint32_t span = 9u;
    uint32_t mult = (65536u % span);
    mult = (mult * mult) % span;
    uint32_t off = ((hi % span) * mult + (lo % span)) % span;
    pc.idx = (int)off;
  }

  kA<<<NBLK_A, 256, 0, stream>>>(x, t, ratio, life, inten, out, bmax,
                                 sk[0][0], sk[0][1], sk[1][0], sk[1][1]);
  kC<<<X4_SIZE / 256, 256, 0, stream>>>(bgf, t, ratio, out, bmax, pc);
}